// Round 2
// baseline (634.172 us; speedup 1.0000x reference)
//
#include <hip/hip_runtime.h>

// Horizon_AttentionPooling: block-diagonal attention.
// T=2048, NUM_SEG=64, SEG=32, F_DIM=32, H_DIM=128, FEAT_DIM=4.
// same_seg masking -> only diagonal 32x32 blocks of the 2048x2048 attention
// matrix survive; seg_size==32>1 always -> final zeroing never applies.
// Effective traffic: f-diag 8 MB + features ~1 MB + hor 0.25 MB + h 1 MB +
// out 1 MB ~= 11 MB -> ~2 us BW floor; kernel is latency-bound, so all
// global loads are hoisted ahead of the LDS phases.

#define TT 2048
#define SEG 32
#define FD 32
#define HD 128

__global__ __launch_bounds__(256) void horizon_attn_kernel(
    const float* __restrict__ f, const float* __restrict__ h,
    const float* __restrict__ features, const float* __restrict__ hor,
    const float* __restrict__ Ww, const float* __restrict__ Wb,
    float* __restrict__ out)
{
    __shared__ float sh_h[SEG][HD];        // 16 KB: h rows of this segment
    __shared__ float sh_Wh[SEG][FD + 1];   // +1 pad breaks bank stride
    __shared__ float sh_attn[8][SEG];

    const int tid = threadIdx.x;
    const int seg = blockIdx.x >> 2;                       // 4 blocks/segment
    const int rowBase = seg * SEG + (blockIdx.x & 3) * 8;  // 8 rows/block
    const int j0 = seg * SEG;

    const int r  = tid >> 5;        // 0..7  row within block
    const int jj = tid & 31;        // 0..31 col within segment
    const int i  = rowBase + r;
    const int j  = j0 + jj;

    // ---- hoist ALL global loads: issue before any LDS phase ----
    const float* frow = f + ((size_t)i * TT + j) * FD;  // 128 B contiguous
    float4 fv[8];
    #pragma unroll
    for (int k = 0; k < 8; ++k) fv[k] = ((const float4*)frow)[k];
    const float dist = features[((size_t)i * TT + j) * 4];  // [...,0]
    const float hb   = hor[(size_t)i * TT + j];

    // ---- stage h[j0:j0+32,:] into LDS (16 KB, float4 coalesced) ----
    {
        const float4* hseg = (const float4*)(h + (size_t)j0 * HD);
        float4* shh4 = (float4*)&sh_h[0][0];
        for (int v = tid; v < (SEG * HD) / 4; v += 256) shh4[v] = hseg[v];
    }
    __syncthreads();

    // ---- Wh[jj][ff] = h[j0+jj,:] . Ww[ff,:] + Wb[ff]  (32x32 values) ----
    {
        const int wjj = tid >> 5, ff = tid & 31;            // one value/thread
        const float4* wrow = (const float4*)(Ww + ff * HD);
        const float4* hrow = (const float4*)sh_h[wjj];
        float acc = 0.f;
        #pragma unroll
        for (int d = 0; d < HD / 4; ++d) {
            const float4 w = wrow[d], hh = hrow[d];
            acc += w.x * hh.x + w.y * hh.y + w.z * hh.z + w.w * hh.w;
        }
        // 256 threads cover 8 jj rows; loop over remaining 24 rows
        #pragma unroll
        for (int rep = 0; rep < 4; ++rep) {
            const int myjj = wjj + rep * 8;
            if (rep) {
                const float4* hr = (const float4*)sh_h[myjj];
                acc = 0.f;
                #pragma unroll
                for (int d = 0; d < HD / 4; ++d) {
                    const float4 w = wrow[d], hh = hr[d];
                    acc += w.x * hh.x + w.y * hh.y + w.z * hh.z + w.w * hh.w;
                }
            }
            sh_Wh[myjj][ff] = acc + Wb[ff];
        }
    }
    __syncthreads();

    // ---- logit + mask + 32-wide softmax ----
    float logit = 0.f;
    #pragma unroll
    for (int k = 0; k < 8; ++k) {
        logit += fv[k].x * sh_Wh[jj][4 * k]     + fv[k].y * sh_Wh[jj][4 * k + 1]
               + fv[k].z * sh_Wh[jj][4 * k + 2] + fv[k].w * sh_Wh[jj][4 * k + 3];
    }
    const bool bad = (hb < 0.f) | (dist > 10.f) | (i == j);
    const float m = bad ? -1000.f : logit;

    float mx = m;
    #pragma unroll
    for (int mask = 16; mask; mask >>= 1) mx = fmaxf(mx, __shfl_xor(mx, mask));
    const float e = __expf(m - mx);
    float s = e;
    #pragma unroll
    for (int mask = 16; mask; mask >>= 1) s += __shfl_xor(s, mask);
    sh_attn[r][jj] = e / s;
    __syncthreads();

    // ---- S[i,:] = sum_jj attn[jj]*h[j0+jj,:]; each thread owns 4 dims ----
    const int d0 = jj * 4;
    float4 acc = make_float4(0.f, 0.f, 0.f, 0.f);
    #pragma unroll 8
    for (int q = 0; q < SEG; ++q) {
        const float a = sh_attn[r][q];
        const float4 hv = *(const float4*)&sh_h[q][d0];
        acc.x += a * hv.x; acc.y += a * hv.y;
        acc.z += a * hv.z; acc.w += a * hv.w;
    }
    *(float4*)(out + (size_t)i * HD + d0) = acc;
}

extern "C" void kernel_launch(void* const* d_in, const int* in_sizes, int n_in,
                              void* d_out, int out_size, void* d_ws, size_t ws_size,
                              hipStream_t stream) {
    const float* f        = (const float*)d_in[0];
    const float* h        = (const float*)d_in[1];
    const float* features = (const float*)d_in[2];
    const float* hor      = (const float*)d_in[3];
    const float* Ww       = (const float*)d_in[4];
    const float* Wb       = (const float*)d_in[5];
    float* out = (float*)d_out;

    hipLaunchKernelGGL(horizon_attn_kernel, dim3(256), dim3(256), 0, stream,
                       f, h, features, hor, Ww, Wb, out);
}